// Round 1
// baseline (1167.921 us; speedup 1.0000x reference)
//
#include <hip/hip_runtime.h>

constexpr int C = 64;    // channels
constexpr int C4 = 16;   // float4s per row

// ---------------------------------------------------------------- degree ----
__global__ void k_deg(const int* __restrict__ col, const float* __restrict__ w,
                      float* __restrict__ deg, int E) {
    int e = blockIdx.x * blockDim.x + threadIdx.x;
    if (e < E) atomicAdd(&deg[col[e]], w[e]);
}

// ---------------------------------------- dinv + self-loop agg init ---------
__global__ void k_init(const float4* __restrict__ x4, const float* __restrict__ deg,
                       float* __restrict__ dinv, float4* __restrict__ agg4, int N) {
    int t = blockIdx.x * blockDim.x + threadIdx.x;
    int v = t >> 4, c4 = t & 15;
    if (v >= N) return;
    float d = rsqrtf(deg[v] + 1.0f);   // +1 = self-loop weight
    if (c4 == 0) dinv[v] = d;
    float s = d * d;                    // self-loop norm = dinv*1*dinv
    float4 xv = x4[v * C4 + c4];
    float4 o; o.x = xv.x * s; o.y = xv.y * s; o.z = xv.z * s; o.w = xv.w * s;
    agg4[v * C4 + c4] = o;
}

// ------------------------------------------------- per-edge coefficient ----
__global__ void k_coef(const int* __restrict__ row, const int* __restrict__ col,
                       const float* __restrict__ w, const float* __restrict__ dinv,
                       float* __restrict__ coef, int E) {
    int e = blockIdx.x * blockDim.x + threadIdx.x;
    if (e < E) coef[e] = dinv[row[e]] * w[e] * dinv[col[e]];
}

// ---------------------------------------------------- edge scatter-add ------
// 16 threads per edge, each handles 4 channels (one float4 of x[col]).
__global__ void k_scatter(const int* __restrict__ row, const int* __restrict__ col,
                          const float* __restrict__ coef, const float4* __restrict__ x4,
                          float* __restrict__ agg, int E) {
    int t = blockIdx.x * blockDim.x + threadIdx.x;
    int e = t >> 4, sub = t & 15;
    if (e >= E) return;
    int r = row[e], c = col[e];
    float cf = coef[e];
    float4 xv = x4[c * C4 + sub];
    float* dst = agg + r * C + sub * 4;
    atomicAdd(dst + 0, xv.x * cf);
    atomicAdd(dst + 1, xv.y * cf);
    atomicAdd(dst + 2, xv.z * cf);
    atomicAdd(dst + 3, xv.w * cf);
}

// -------------------------------------- h = 0.9*agg + 0.1*x ; relu(h @ W) ---
// Block: 256 threads -> 64 nodes x 64 cols, 4x4 register tile per thread.
__global__ __launch_bounds__(256) void k_mm(const float4* __restrict__ agg4,
                                            const float4* __restrict__ x4,
                                            const float4* __restrict__ W4,
                                            float4* __restrict__ out4, int N) {
    __shared__ float Ws[C * C];       // 16 KB, W row-major
    __shared__ float hs[64 * 68];     // 17.4 KB, stride 68 (bank decorrelation)
    const int tid = threadIdx.x;
    const int base = blockIdx.x * 64;

    // stage W (1024 float4s)
    #pragma unroll
    for (int i = 0; i < 4; ++i) {
        int f = tid + i * 256;
        ((float4*)Ws)[f] = W4[f];
    }
    // stage h-tile: h = 0.9*agg + 0.1*x
    #pragma unroll
    for (int i = 0; i < 4; ++i) {
        int f = tid + i * 256;        // 1024 float4s: vl = f/16, c4 = f%16
        int vl = f >> 4, c4 = f & 15;
        int v = base + vl;
        float4 h;
        if (v < N) {
            float4 a = agg4[v * C4 + c4];
            float4 xx = x4[v * C4 + c4];
            h.x = 0.9f * a.x + 0.1f * xx.x;
            h.y = 0.9f * a.y + 0.1f * xx.y;
            h.z = 0.9f * a.z + 0.1f * xx.z;
            h.w = 0.9f * a.w + 0.1f * xx.w;
        } else {
            h.x = h.y = h.z = h.w = 0.0f;
        }
        *(float4*)&hs[vl * 68 + c4 * 4] = h;
    }
    __syncthreads();

    const int tc = tid & 15;   // col quad:  cols tc*4 .. tc*4+3
    const int tn = tid >> 4;   // node quad: nodes tn*4 .. tn*4+3
    float4 acc[4];
    #pragma unroll
    for (int i = 0; i < 4; ++i) { acc[i].x = acc[i].y = acc[i].z = acc[i].w = 0.0f; }

    #pragma unroll
    for (int k4 = 0; k4 < 16; ++k4) {
        float4 wv0 = *(const float4*)&Ws[(k4 * 4 + 0) * C + tc * 4];
        float4 wv1 = *(const float4*)&Ws[(k4 * 4 + 1) * C + tc * 4];
        float4 wv2 = *(const float4*)&Ws[(k4 * 4 + 2) * C + tc * 4];
        float4 wv3 = *(const float4*)&Ws[(k4 * 4 + 3) * C + tc * 4];
        #pragma unroll
        for (int i = 0; i < 4; ++i) {
            float4 hv = *(const float4*)&hs[(tn * 4 + i) * 68 + k4 * 4];
            acc[i].x += hv.x * wv0.x + hv.y * wv1.x + hv.z * wv2.x + hv.w * wv3.x;
            acc[i].y += hv.x * wv0.y + hv.y * wv1.y + hv.z * wv2.y + hv.w * wv3.y;
            acc[i].z += hv.x * wv0.z + hv.y * wv1.z + hv.z * wv2.z + hv.w * wv3.z;
            acc[i].w += hv.x * wv0.w + hv.y * wv1.w + hv.z * wv2.w + hv.w * wv3.w;
        }
    }

    #pragma unroll
    for (int i = 0; i < 4; ++i) {
        int v = base + tn * 4 + i;
        if (v < N) {
            float4 o;
            o.x = fmaxf(acc[i].x, 0.0f);
            o.y = fmaxf(acc[i].y, 0.0f);
            o.z = fmaxf(acc[i].z, 0.0f);
            o.w = fmaxf(acc[i].w, 0.0f);
            out4[v * C4 + tc] = o;
        }
    }
}

// ----------------------------------------------------------------------------
extern "C" void kernel_launch(void* const* d_in, const int* in_sizes, int n_in,
                              void* d_out, int out_size, void* d_ws, size_t ws_size,
                              hipStream_t stream) {
    const float* x  = (const float*)d_in[0];
    const int*   ei = (const int*)d_in[1];   // [2,E]: row then col
    const float* ew = (const float*)d_in[2];
    const float* W  = (const float*)d_in[3];

    const int N = in_sizes[0] / C;
    const int E = in_sizes[1] / 2;
    const int* row = ei;
    const int* col = ei + E;
    float* out = (float*)d_out;

    // workspace: deg[N] | dinv[N] | coef[E] | agg[N*C]   (all fp32, 16B aligned)
    float* deg  = (float*)d_ws;
    float* dinv = deg + N;
    float* coef = dinv + N;
    float* agg  = coef + E;   // offset (2N+E)*4 bytes = 5.6MB, 16B aligned

    hipMemsetAsync(deg, 0, (size_t)N * sizeof(float), stream);

    k_deg<<<(E + 255) / 256, 256, 0, stream>>>(col, ew, deg, E);
    k_init<<<(N * 16 + 255) / 256, 256, 0, stream>>>(
        (const float4*)x, deg, dinv, (float4*)agg, N);
    k_coef<<<(E + 255) / 256, 256, 0, stream>>>(row, col, ew, dinv, coef, E);
    k_scatter<<<(E * 16 + 255) / 256, 256, 0, stream>>>(
        row, col, coef, (const float4*)x, agg, E);
    k_mm<<<(N + 63) / 64, 256, 0, stream>>>(
        (const float4*)agg, (const float4*)x, (const float4*)W, (float4*)out, N);
}

// Round 2
// 539.115 us; speedup vs baseline: 2.1664x; 2.1664x over previous
//
#include <hip/hip_runtime.h>

constexpr int C = 64;    // channels
constexpr int C4 = 16;   // float4s per row

// ---------------------------------------------------------------- count -----
// deg[col] += w  (for symmetric norm)   and   cnt[row] += 1  (for CSR)
__global__ void k_count(const int* __restrict__ row, const int* __restrict__ col,
                        const float* __restrict__ w,
                        float* __restrict__ deg, int* __restrict__ cnt, int E) {
    int e = blockIdx.x * blockDim.x + threadIdx.x;
    if (e < E) {
        atomicAdd(&deg[col[e]], w[e]);
        atomicAdd(&cnt[row[e]], 1);
    }
}

// ---------------------------------------------------------------- scan ------
// Single-block exclusive scan of cnt[N] -> rowptr[N+1], plus cursor copy.
__global__ __launch_bounds__(1024) void k_scan(const int* __restrict__ cnt,
                                               int* __restrict__ rowptr,
                                               int* __restrict__ cursor, int N) {
    __shared__ int part[1024];
    const int tid = threadIdx.x;
    const int chunk = (N + 1023) >> 10;
    const int lo = tid * chunk;
    const int hi = min(lo + chunk, N);
    int s = 0;
    for (int i = lo; i < hi; ++i) s += cnt[i];
    part[tid] = s;
    __syncthreads();
    // Hillis-Steele inclusive scan over 1024 partials
    for (int d = 1; d < 1024; d <<= 1) {
        int v = (tid >= d) ? part[tid - d] : 0;
        __syncthreads();
        part[tid] += v;
        __syncthreads();
    }
    int off = (tid > 0) ? part[tid - 1] : 0;
    for (int i = lo; i < hi; ++i) {
        int c = cnt[i];
        rowptr[i] = off;
        cursor[i] = off;
        off += c;
    }
    if (tid == 1023) rowptr[N] = part[1023];
}

// ---------------------------------------------------------------- dinv ------
__global__ void k_dinv(const float* __restrict__ deg, float* __restrict__ dinv, int N) {
    int v = blockIdx.x * blockDim.x + threadIdx.x;
    if (v < N) dinv[v] = rsqrtf(deg[v] + 1.0f);   // +1 = self-loop weight
}

// ---------------------------------------------------------------- fill ------
// Scatter edges into CSR slots; precompute coef = dinv[r]*w*dinv[c].
__global__ void k_fill(const int* __restrict__ row, const int* __restrict__ col,
                       const float* __restrict__ w, const float* __restrict__ dinv,
                       int* __restrict__ cursor, int* __restrict__ ecol,
                       float* __restrict__ ecoef, int E) {
    int e = blockIdx.x * blockDim.x + threadIdx.x;
    if (e >= E) return;
    int r = row[e], c = col[e];
    int pos = atomicAdd(&cursor[r], 1);
    ecol[pos]  = c;
    ecoef[pos] = dinv[r] * w[e] * dinv[c];
}

// ---------------------------------------------------------------- gather ----
// One wave per node; lane = channel. h = 0.9*(agg incl self-loop) + 0.1*x.
// Writes h directly into d_out (k_mm then runs in place).
__global__ __launch_bounds__(256) void k_gather(const int* __restrict__ rowptr,
                                                const int* __restrict__ ecol,
                                                const float* __restrict__ ecoef,
                                                const float* __restrict__ x,
                                                const float* __restrict__ dinv,
                                                float* __restrict__ h, int N) {
    int v = (blockIdx.x * blockDim.x + threadIdx.x) >> 6;
    int lane = threadIdx.x & 63;
    if (v >= N) return;
    int beg = rowptr[v], end = rowptr[v + 1];
    float dv = dinv[v];
    float xs = x[(size_t)v * C + lane];
    float acc = dv * dv * xs;             // self-loop contribution
    int j = beg;
    for (; j + 3 < end; j += 4) {         // 4 independent gathers in flight
        int   c0 = ecol[j],     c1 = ecol[j + 1],  c2 = ecol[j + 2],  c3 = ecol[j + 3];
        float f0 = ecoef[j],    f1 = ecoef[j + 1], f2 = ecoef[j + 2], f3 = ecoef[j + 3];
        float x0 = x[(size_t)c0 * C + lane];
        float x1 = x[(size_t)c1 * C + lane];
        float x2 = x[(size_t)c2 * C + lane];
        float x3 = x[(size_t)c3 * C + lane];
        acc += f0 * x0; acc += f1 * x1; acc += f2 * x2; acc += f3 * x3;
    }
    for (; j < end; ++j)
        acc += ecoef[j] * x[(size_t)ecol[j] * C + lane];
    h[(size_t)v * C + lane] = 0.9f * acc + 0.1f * xs;
}

// -------------------------------------------- out = relu(h @ W), in place ---
// Block: 256 threads -> 64 nodes x 64 cols, 4x4 register tile per thread.
__global__ __launch_bounds__(256) void k_mm(float4* __restrict__ io4,
                                            const float4* __restrict__ W4, int N) {
    __shared__ float Ws[C * C];       // 16 KB
    __shared__ float hs[64 * 68];     // stride 68 for bank decorrelation
    const int tid = threadIdx.x;
    const int base = blockIdx.x * 64;

    #pragma unroll
    for (int i = 0; i < 4; ++i) {
        int f = tid + i * 256;
        ((float4*)Ws)[f] = W4[f];
    }
    #pragma unroll
    for (int i = 0; i < 4; ++i) {
        int f = tid + i * 256;
        int vl = f >> 4, c4 = f & 15;
        int v = base + vl;
        float4 hv;
        if (v < N) hv = io4[(size_t)v * C4 + c4];
        else       hv.x = hv.y = hv.z = hv.w = 0.0f;
        *(float4*)&hs[vl * 68 + c4 * 4] = hv;
    }
    __syncthreads();

    const int tc = tid & 15;
    const int tn = tid >> 4;
    float4 acc[4];
    #pragma unroll
    for (int i = 0; i < 4; ++i) { acc[i].x = acc[i].y = acc[i].z = acc[i].w = 0.0f; }

    #pragma unroll
    for (int k4 = 0; k4 < 16; ++k4) {
        float4 wv0 = *(const float4*)&Ws[(k4 * 4 + 0) * C + tc * 4];
        float4 wv1 = *(const float4*)&Ws[(k4 * 4 + 1) * C + tc * 4];
        float4 wv2 = *(const float4*)&Ws[(k4 * 4 + 2) * C + tc * 4];
        float4 wv3 = *(const float4*)&Ws[(k4 * 4 + 3) * C + tc * 4];
        #pragma unroll
        for (int i = 0; i < 4; ++i) {
            float4 hv = *(const float4*)&hs[(tn * 4 + i) * 68 + k4 * 4];
            acc[i].x += hv.x * wv0.x + hv.y * wv1.x + hv.z * wv2.x + hv.w * wv3.x;
            acc[i].y += hv.x * wv0.y + hv.y * wv1.y + hv.z * wv2.y + hv.w * wv3.y;
            acc[i].z += hv.x * wv0.z + hv.y * wv1.z + hv.z * wv2.z + hv.w * wv3.z;
            acc[i].w += hv.x * wv0.w + hv.y * wv1.w + hv.z * wv2.w + hv.w * wv3.w;
        }
    }

    #pragma unroll
    for (int i = 0; i < 4; ++i) {
        int v = base + tn * 4 + i;
        if (v < N) {
            float4 o;
            o.x = fmaxf(acc[i].x, 0.0f);
            o.y = fmaxf(acc[i].y, 0.0f);
            o.z = fmaxf(acc[i].z, 0.0f);
            o.w = fmaxf(acc[i].w, 0.0f);
            io4[(size_t)v * C4 + tc] = o;
        }
    }
}

// ----------------------------------------------------------------------------
extern "C" void kernel_launch(void* const* d_in, const int* in_sizes, int n_in,
                              void* d_out, int out_size, void* d_ws, size_t ws_size,
                              hipStream_t stream) {
    const float* x  = (const float*)d_in[0];
    const int*   ei = (const int*)d_in[1];   // [2,E]: row then col
    const float* ew = (const float*)d_in[2];
    const float* W  = (const float*)d_in[3];

    const int N = in_sizes[0] / C;
    const int E = in_sizes[1] / 2;
    const int* row = ei;
    const int* col = ei + E;
    float* out = (float*)d_out;

    // workspace layout (all 4-byte elems):
    // deg[N] | dinv[N] | cnt[N] | rowptr[N+1] | cursor[N] | ecol[E] | ecoef[E]
    float* deg    = (float*)d_ws;
    float* dinv   = deg + N;
    int*   cnt    = (int*)(dinv + N);
    int*   rowptr = cnt + N;
    int*   cursor = rowptr + (N + 1);
    int*   ecol   = cursor + N;
    float* ecoef  = (float*)(ecol + E);

    hipMemsetAsync(deg, 0, (size_t)N * sizeof(float), stream);
    hipMemsetAsync(cnt, 0, (size_t)N * sizeof(int), stream);

    k_count<<<(E + 255) / 256, 256, 0, stream>>>(row, col, ew, deg, cnt, E);
    k_scan<<<1, 1024, 0, stream>>>(cnt, rowptr, cursor, N);
    k_dinv<<<(N + 255) / 256, 256, 0, stream>>>(deg, dinv, N);
    k_fill<<<(E + 255) / 256, 256, 0, stream>>>(row, col, ew, dinv, cursor, ecol, ecoef, E);
    k_gather<<<(N * 64 + 255) / 256, 256, 0, stream>>>(rowptr, ecol, ecoef, x, dinv, out, N);
    k_mm<<<(N + 63) / 64, 256, 0, stream>>>((float4*)out, (const float4*)W, N);
}

// Round 3
// 326.685 us; speedup vs baseline: 3.5751x; 1.6503x over previous
//
#include <hip/hip_runtime.h>

constexpr int C = 64;    // channels
constexpr int C4 = 16;   // float4s per row
constexpr int SCAN_TILE = 2048;   // elems per scan block (256 thr x 8)

// ---------------------------------------------------------------- count -----
__global__ void k_count(const int* __restrict__ row, const int* __restrict__ col,
                        const float* __restrict__ w,
                        float* __restrict__ deg, int* __restrict__ cnt, int E) {
    int e = blockIdx.x * blockDim.x + threadIdx.x;
    if (e < E) {
        atomicAdd(&deg[col[e]], w[e]);
        atomicAdd(&cnt[row[e]], 1);
    }
}

// ------------------------------------------------------- multi-block scan ---
__global__ __launch_bounds__(256) void k_scanA(const int* __restrict__ cnt,
                                               int* __restrict__ bsum, int N) {
    __shared__ int red[256];
    int t = threadIdx.x;
    int base = blockIdx.x * SCAN_TILE + t * 8;
    int s = 0;
    #pragma unroll
    for (int i = 0; i < 8; ++i) { int idx = base + i; if (idx < N) s += cnt[idx]; }
    red[t] = s;
    __syncthreads();
    for (int d = 128; d > 0; d >>= 1) {
        if (t < d) red[t] += red[t + d];
        __syncthreads();
    }
    if (t == 0) bsum[blockIdx.x] = red[0];
}

__global__ void k_scanB(const int* __restrict__ bsum, int* __restrict__ boff,
                        int nb, int* __restrict__ rowptr_end) {
    if (threadIdx.x == 0) {
        int acc = 0;
        for (int b = 0; b < nb; ++b) { boff[b] = acc; acc += bsum[b]; }
        *rowptr_end = acc;    // rowptr[N] = E
    }
}

__global__ __launch_bounds__(256) void k_scanC(const int* __restrict__ cnt,
                                               const int* __restrict__ boff,
                                               int* __restrict__ rowptr,
                                               int* __restrict__ cursor, int N) {
    __shared__ int tsum[256];
    int t = threadIdx.x;
    int base = blockIdx.x * SCAN_TILE + t * 8;
    int v[8];
    int s = 0;
    #pragma unroll
    for (int i = 0; i < 8; ++i) {
        int idx = base + i;
        v[i] = (idx < N) ? cnt[idx] : 0;
        s += v[i];
    }
    tsum[t] = s;
    __syncthreads();
    for (int d = 1; d < 256; d <<= 1) {
        int other = (t >= d) ? tsum[t - d] : 0;
        __syncthreads();
        tsum[t] += other;
        __syncthreads();
    }
    int excl = tsum[t] - s + boff[blockIdx.x];
    #pragma unroll
    for (int i = 0; i < 8; ++i) {
        int idx = base + i;
        if (idx < N) {
            rowptr[idx] = excl;
            cursor[idx] = excl;
            excl += v[i];
        }
    }
}

// ---------------------------------------------------------------- dinv ------
__global__ void k_dinv(const float* __restrict__ deg, float* __restrict__ dinv, int N) {
    int v = blockIdx.x * blockDim.x + threadIdx.x;
    if (v < N) dinv[v] = rsqrtf(deg[v] + 1.0f);   // +1 = self-loop weight
}

// ---------------------------------------------------------------- fill ------
__global__ void k_fill(const int* __restrict__ row, const int* __restrict__ col,
                       const float* __restrict__ w, const float* __restrict__ dinv,
                       int* __restrict__ cursor, int* __restrict__ ecol,
                       float* __restrict__ ecoef, int E) {
    int e = blockIdx.x * blockDim.x + threadIdx.x;
    if (e >= E) return;
    int r = row[e], c = col[e];
    int pos = atomicAdd(&cursor[r], 1);
    ecol[pos]  = c;
    ecoef[pos] = dinv[r] * w[e] * dinv[c];
}

// ---------------------------------------------------------------- gather ----
// One wave per node; lane = channel. h = 0.9*(agg incl self-loop) + 0.1*x.
__global__ __launch_bounds__(256) void k_gather(const int* __restrict__ rowptr,
                                                const int* __restrict__ ecol,
                                                const float* __restrict__ ecoef,
                                                const float* __restrict__ x,
                                                const float* __restrict__ dinv,
                                                float* __restrict__ h, int N) {
    int v = (blockIdx.x * blockDim.x + threadIdx.x) >> 6;
    int lane = threadIdx.x & 63;
    if (v >= N) return;
    int beg = rowptr[v], end = rowptr[v + 1];
    float dv = dinv[v];
    float xs = x[(size_t)v * C + lane];
    float acc = dv * dv * xs;             // self-loop contribution
    int j = beg;
    for (; j + 3 < end; j += 4) {
        int   c0 = ecol[j],     c1 = ecol[j + 1],  c2 = ecol[j + 2],  c3 = ecol[j + 3];
        float f0 = ecoef[j],    f1 = ecoef[j + 1], f2 = ecoef[j + 2], f3 = ecoef[j + 3];
        float x0 = x[(size_t)c0 * C + lane];
        float x1 = x[(size_t)c1 * C + lane];
        float x2 = x[(size_t)c2 * C + lane];
        float x3 = x[(size_t)c3 * C + lane];
        acc += f0 * x0; acc += f1 * x1; acc += f2 * x2; acc += f3 * x3;
    }
    for (; j < end; ++j)
        acc += ecoef[j] * x[(size_t)ecol[j] * C + lane];
    h[(size_t)v * C + lane] = 0.9f * acc + 0.1f * xs;
}

// -------------------------------------------- out = relu(h @ W), in place ---
__global__ __launch_bounds__(256) void k_mm(float4* __restrict__ io4,
                                            const float4* __restrict__ W4, int N) {
    __shared__ float Ws[C * C];
    __shared__ float hs[64 * 68];
    const int tid = threadIdx.x;
    const int base = blockIdx.x * 64;

    #pragma unroll
    for (int i = 0; i < 4; ++i) {
        int f = tid + i * 256;
        ((float4*)Ws)[f] = W4[f];
    }
    #pragma unroll
    for (int i = 0; i < 4; ++i) {
        int f = tid + i * 256;
        int vl = f >> 4, c4 = f & 15;
        int v = base + vl;
        float4 hv;
        if (v < N) hv = io4[(size_t)v * C4 + c4];
        else       hv.x = hv.y = hv.z = hv.w = 0.0f;
        *(float4*)&hs[vl * 68 + c4 * 4] = hv;
    }
    __syncthreads();

    const int tc = tid & 15;
    const int tn = tid >> 4;
    float4 acc[4];
    #pragma unroll
    for (int i = 0; i < 4; ++i) { acc[i].x = acc[i].y = acc[i].z = acc[i].w = 0.0f; }

    #pragma unroll
    for (int k4 = 0; k4 < 16; ++k4) {
        float4 wv0 = *(const float4*)&Ws[(k4 * 4 + 0) * C + tc * 4];
        float4 wv1 = *(const float4*)&Ws[(k4 * 4 + 1) * C + tc * 4];
        float4 wv2 = *(const float4*)&Ws[(k4 * 4 + 2) * C + tc * 4];
        float4 wv3 = *(const float4*)&Ws[(k4 * 4 + 3) * C + tc * 4];
        #pragma unroll
        for (int i = 0; i < 4; ++i) {
            float4 hv = *(const float4*)&hs[(tn * 4 + i) * 68 + k4 * 4];
            acc[i].x += hv.x * wv0.x + hv.y * wv1.x + hv.z * wv2.x + hv.w * wv3.x;
            acc[i].y += hv.x * wv0.y + hv.y * wv1.y + hv.z * wv2.y + hv.w * wv3.y;
            acc[i].z += hv.x * wv0.z + hv.y * wv1.z + hv.z * wv2.z + hv.w * wv3.z;
            acc[i].w += hv.x * wv0.w + hv.y * wv1.w + hv.z * wv2.w + hv.w * wv3.w;
        }
    }

    #pragma unroll
    for (int i = 0; i < 4; ++i) {
        int v = base + tn * 4 + i;
        if (v < N) {
            float4 o;
            o.x = fmaxf(acc[i].x, 0.0f);
            o.y = fmaxf(acc[i].y, 0.0f);
            o.z = fmaxf(acc[i].z, 0.0f);
            o.w = fmaxf(acc[i].w, 0.0f);
            io4[(size_t)v * C4 + tc] = o;
        }
    }
}

// ----------------------------------------------------------------------------
extern "C" void kernel_launch(void* const* d_in, const int* in_sizes, int n_in,
                              void* d_out, int out_size, void* d_ws, size_t ws_size,
                              hipStream_t stream) {
    const float* x  = (const float*)d_in[0];
    const int*   ei = (const int*)d_in[1];   // [2,E]: row then col
    const float* ew = (const float*)d_in[2];
    const float* W  = (const float*)d_in[3];

    const int N = in_sizes[0] / C;
    const int E = in_sizes[1] / 2;
    const int* row = ei;
    const int* col = ei + E;
    float* out = (float*)d_out;

    const int nb = (N + SCAN_TILE - 1) / SCAN_TILE;   // scan blocks (~49)

    // workspace layout (4-byte elems):
    // deg[N] | dinv[N] | cnt[N] | rowptr[N+1] | cursor[N] | bsum[nb] | boff[nb]
    // | ecol[E] | ecoef[E]
    float* deg    = (float*)d_ws;
    float* dinv   = deg + N;
    int*   cnt    = (int*)(dinv + N);
    int*   rowptr = cnt + N;
    int*   cursor = rowptr + (N + 1);
    int*   bsum   = cursor + N;
    int*   boff   = bsum + nb;
    int*   ecol   = boff + nb;
    float* ecoef  = (float*)(ecol + E);

    hipMemsetAsync(deg, 0, (size_t)N * sizeof(float), stream);
    hipMemsetAsync(cnt, 0, (size_t)N * sizeof(int), stream);

    k_count<<<(E + 255) / 256, 256, 0, stream>>>(row, col, ew, deg, cnt, E);
    k_scanA<<<nb, 256, 0, stream>>>(cnt, bsum, N);
    k_scanB<<<1, 64, 0, stream>>>(bsum, boff, nb, rowptr + N);
    k_scanC<<<nb, 256, 0, stream>>>(cnt, boff, rowptr, cursor, N);
    k_dinv<<<(N + 255) / 256, 256, 0, stream>>>(deg, dinv, N);
    k_fill<<<(E + 255) / 256, 256, 0, stream>>>(row, col, ew, dinv, cursor, ecol, ecoef, E);
    k_gather<<<(N * 64 + 255) / 256, 256, 0, stream>>>(rowptr, ecol, ecoef, x, dinv, out, N);
    k_mm<<<(N + 63) / 64, 256, 0, stream>>>((float4*)out, (const float4*)W, N);
}